// Round 19
// baseline (66.163 us; speedup 1.0000x reference)
//
#include <hip/hip_runtime.h>

#define K_DIM   4096
#define N_DIM   4096
#define M_ROWS  8192
#define KF      (K_DIM / 4)      // 1024 float4 per x/A row
#define NF      (N_DIM / 4)      // 1024 float4 per out/Bt row

typedef __attribute__((ext_vector_type(8))) short short8v;   // 8 bf16
typedef __attribute__((ext_vector_type(4))) float f32x4;

// round-to-nearest-even fp32 -> bf16 bits
static __device__ __forceinline__ short f2bf(float f) {
    const unsigned u = __builtin_bit_cast(unsigned, f);
    return (short)((u + 0x7FFFu + ((u >> 16) & 1u)) >> 16);
}

__device__ __forceinline__ void fma_s4(float4& o, float s, const float4 b) {
    o.x = fmaf(s, b.x, o.x);
    o.y = fmaf(s, b.y, o.y);
    o.z = fmaf(s, b.z, o.z);
    o.w = fmaf(s, b.w, o.w);
}

// ---------------------------------------------------------------------------
// Prep: transpose B [4096][16] -> Bt [16][4096]  (256 KB, ~2 us)
__global__ __launch_bounds__(256) void lora_prep(const float* __restrict__ B,
                                                 float* __restrict__ Bt) {
    const int i4 = blockIdx.x * 256 + threadIdx.x;   // 0..16383
    const int r  = i4 >> 10;             // Bt row 0..15
    const int c0 = (i4 & 1023) * 4;      // first of 4 cols
    float4 v;
    v.x = B[(size_t)(c0 + 0) * 16 + r];
    v.y = B[(size_t)(c0 + 1) * 16 + r];
    v.z = B[(size_t)(c0 + 2) * 16 + r];
    v.w = B[(size_t)(c0 + 3) * 16 + r];
    ((float4*)Bt)[i4] = v;
}

// ---------------------------------------------------------------------------
// Fused LoRA, 8-wave blocks (round-18 occupancy fix):
//   512 blocks x 512 thr -> 2 blocks/CU x 8 waves = 16 waves/CU (4/SIMD),
//   the VGPR=100 occupancy ceiling. Per-wave phase-1 chain halves to 16
//   MFMA iters (K-eighth). Phase 2 register-lean (proven r18: no spill).
__global__ __launch_bounds__(512) void lora_fused(const float* __restrict__ x,
                                                  const float* __restrict__ A,
                                                  const float* __restrict__ Bt,
                                                  float* __restrict__ out) {
    __shared__ float part[8][256];        // per-wave t partials, 8 KB
    __shared__ float t_s[256];            // reduced t tile: [row][r], 1 KB

    const int tid  = threadIdx.x;         // 0..511
    const int wv   = tid >> 6;            // K eighth 0..7
    const int lane = tid & 63;
    const int row0 = blockIdx.x * 16;

    const int mrow = row0 + (lane & 15);  // x row this lane feeds (A-op)
    const int acol = lane & 15;           // A row = t column (B-op)
    const int og   = (lane >> 4) * 2;     // float4 pair within K=32 octet

    const float4* x4 = (const float4*)x;
    const float4* A4 = (const float4*)A;
    const size_t xbase = (size_t)mrow * KF;
    const size_t abase = (size_t)acol * KF;
    const int kq = wv * 128;              // K-eighth base in float4 units

    f32x4 acc = {0.f, 0.f, 0.f, 0.f};

    #pragma unroll 2
    for (int it = 0; it < 16; ++it) {
        const int kf = kq + it * 8 + og;
        const float4 xa = x4[xbase + kf];
        const float4 xb = x4[xbase + kf + 1];
        const float4 aa = A4[abase + kf];
        const float4 ab = A4[abase + kf + 1];

        short8v af, bf;
        af[0] = f2bf(xa.x); af[1] = f2bf(xa.y);
        af[2] = f2bf(xa.z); af[3] = f2bf(xa.w);
        af[4] = f2bf(xb.x); af[5] = f2bf(xb.y);
        af[6] = f2bf(xb.z); af[7] = f2bf(xb.w);
        bf[0] = f2bf(aa.x); bf[1] = f2bf(aa.y);
        bf[2] = f2bf(aa.z); bf[3] = f2bf(aa.w);
        bf[4] = f2bf(ab.x); bf[5] = f2bf(ab.y);
        bf[6] = f2bf(ab.z); bf[7] = f2bf(ab.w);

        acc = __builtin_amdgcn_mfma_f32_16x16x32_bf16(af, bf, acc, 0, 0, 0);
    }

    // C layout: lane l reg v -> local row (l>>4)*4+v, col l&15
    #pragma unroll
    for (int v = 0; v < 4; ++v)
        part[wv][((lane >> 4) * 4 + v) * 16 + (lane & 15)] = acc[v];
    __syncthreads();

    // fixed-order reduction over the 8 K-eighths (threads 0..255)
    if (tid < 256) {
        float s = ((part[0][tid] + part[1][tid]) +
                   (part[2][tid] + part[3][tid])) +
                  ((part[4][tid] + part[5][tid]) +
                   (part[6][tid] + part[7][tid]));
        t_s[tid] = s;
    }
    __syncthreads();

    // ---- phase 2: out[row0..row0+15][:] = t_s @ Bt, register-lean ----
    const float4* Bt4 = (const float4*)Bt;
    const float4* ts4 = (const float4*)t_s;
    float4* out4 = (float4*)out;

    for (int ch = 0; ch < 2; ++ch) {
        const int c4 = ch * 512 + tid;    // float4 column index
        #pragma unroll
        for (int g = 0; g < 2; ++g) {     // 8-row group
            float4 o[8];
            #pragma unroll
            for (int w = 0; w < 8; ++w) o[w] = {0.f, 0.f, 0.f, 0.f};

            // ---- r half 0: Bt rows 0..7 ----
            {
                float4 bv[8];
                #pragma unroll
                for (int r = 0; r < 8; ++r)
                    bv[r] = Bt4[r * NF + c4];        // 2KB bursts, L2-hot
                #pragma unroll
                for (int w = 0; w < 8; ++w) {
                    const float4 tq0 = ts4[(g * 8 + w) * 4 + 0];
                    const float4 tq1 = ts4[(g * 8 + w) * 4 + 1];
                    fma_s4(o[w], tq0.x, bv[0]);
                    fma_s4(o[w], tq0.y, bv[1]);
                    fma_s4(o[w], tq0.z, bv[2]);
                    fma_s4(o[w], tq0.w, bv[3]);
                    fma_s4(o[w], tq1.x, bv[4]);
                    fma_s4(o[w], tq1.y, bv[5]);
                    fma_s4(o[w], tq1.z, bv[6]);
                    fma_s4(o[w], tq1.w, bv[7]);
                }
            }
            __builtin_amdgcn_sched_barrier(0);       // bv half-1 not hoisted
            // ---- r half 1: Bt rows 8..15 ----
            {
                float4 bv[8];
                #pragma unroll
                for (int r = 0; r < 8; ++r)
                    bv[r] = Bt4[(8 + r) * NF + c4];
                #pragma unroll
                for (int w = 0; w < 8; ++w) {
                    const float4 tq2 = ts4[(g * 8 + w) * 4 + 2];
                    const float4 tq3 = ts4[(g * 8 + w) * 4 + 3];
                    fma_s4(o[w], tq2.x, bv[0]);
                    fma_s4(o[w], tq2.y, bv[1]);
                    fma_s4(o[w], tq2.z, bv[2]);
                    fma_s4(o[w], tq2.w, bv[3]);
                    fma_s4(o[w], tq3.x, bv[4]);
                    fma_s4(o[w], tq3.y, bv[5]);
                    fma_s4(o[w], tq3.z, bv[6]);
                    fma_s4(o[w], tq3.w, bv[7]);
                }
            }
            #pragma unroll
            for (int w = 0; w < 8; ++w)
                out4[(size_t)(row0 + g * 8 + w) * NF + c4] = o[w];
        }
    }
}

extern "C" void kernel_launch(void* const* d_in, const int* in_sizes, int n_in,
                              void* d_out, int out_size, void* d_ws, size_t ws_size,
                              hipStream_t stream) {
    const float* x = (const float*)d_in[0];            // [4,2048,4096]
    const float* B = (const float*)d_in[1];            // [4096,16]
    const float* A = (const float*)d_in[2];            // [16,4096]
    float* out = (float*)d_out;                        // [4,2048,4096]

    float* Bt = (float*)d_ws;                          // [16][4096], 256 KB

    lora_prep<<<64, 256, 0, stream>>>(B, Bt);
    lora_fused<<<M_ROWS / 16, 512, 0, stream>>>(x, A, Bt, out);
}

// Round 20
// 62.914 us; speedup vs baseline: 1.0516x; 1.0516x over previous
//
#include <hip/hip_runtime.h>

#define K_DIM   4096
#define N_DIM   4096
#define M_ROWS  8192
#define KF      (K_DIM / 4)      // 1024 float4 per x/A row
#define NF      (N_DIM / 4)      // 1024 float4 per out/Bt row
#define KSPLIT  8
#define NTILES  (M_ROWS / 16)    // 512 row tiles (k2 grid)
#define TP_F4_STRIDE (M_ROWS * 16 / 4)   // 32768 float4 per k-partial slab
#define XAT_BLOCKS ((M_ROWS / 64) * KSPLIT)   // 1024
#define TRB_BLOCKS 64                         // folded B-transpose blocks

typedef __attribute__((ext_vector_type(8))) short short8v;   // 8 bf16
typedef __attribute__((ext_vector_type(4))) float f32x4;
typedef __attribute__((ext_vector_type(4))) unsigned u32x4;

// v_cvt_pk_bf16_f32: packs 2 f32 -> 2 bf16 in one VGPR (lo = first src).
static __device__ __forceinline__ unsigned cvt_pk(float lo, float hi) {
    unsigned r;
    asm("v_cvt_pk_bf16_f32 %0, %1, %2" : "=v"(r) : "v"(lo), "v"(hi));
    return r;
}

// two float4 -> 8 bf16 (4 VGPRs) via 4 cvt_pk ops
static __device__ __forceinline__ short8v pack8(const float4 a, const float4 b) {
    u32x4 p;
    p[0] = cvt_pk(a.x, a.y);
    p[1] = cvt_pk(a.z, a.w);
    p[2] = cvt_pk(b.x, b.y);
    p[3] = cvt_pk(b.z, b.w);
    return __builtin_bit_cast(short8v, p);
}

// ---------------------------------------------------------------------------
// Kernel 1 (MFMA + folded B-transpose), round-13 structure + cvt_pk chain fix.
// Blocks [0, 1024): t partials. Blocks [1024, 1088): B -> Bt transpose.
__global__ __launch_bounds__(256) void lora_xat(const float* __restrict__ x,
                                                const float* __restrict__ A,
                                                const float* __restrict__ B,
                                                float* __restrict__ Bt,
                                                float* __restrict__ tpart) {
    const int tid = threadIdx.x;

    if (blockIdx.x >= XAT_BLOCKS) {
        // ---- B transpose: 64 blocks x 256 thr x 1 float4 of Bt ----
        const int i4 = (blockIdx.x - XAT_BLOCKS) * 256 + tid;  // 0..16383
        const int r  = i4 >> 10;             // Bt row 0..15
        const int c0 = (i4 & 1023) * 4;      // first of 4 cols
        float4 v;
        v.x = B[(size_t)(c0 + 0) * 16 + r];
        v.y = B[(size_t)(c0 + 1) * 16 + r];
        v.z = B[(size_t)(c0 + 2) * 16 + r];
        v.w = B[(size_t)(c0 + 3) * 16 + r];
        ((float4*)Bt)[i4] = v;
        return;
    }

    const int wv   = tid >> 6;
    const int lane = tid & 63;
    const int rb   = blockIdx.x >> 3;     // 64-row tile
    const int h    = blockIdx.x & 7;      // K eighth
    const int row0 = rb * 64 + wv * 16;

    const int mrow = row0 + (lane & 15);  // x row this lane feeds (A-op)
    const int acol = lane & 15;           // A-matrix row = t column (B-op)
    const int og   = (lane >> 4) * 2;     // lane-group's float4 pair in octet

    const float4* x4 = (const float4*)x;
    const float4* A4 = (const float4*)A;
    const size_t xbase = (size_t)mrow * KF;
    const size_t abase = (size_t)acol * KF;

    f32x4 acc = {0.f, 0.f, 0.f, 0.f};

    #pragma unroll 4
    for (int it = 0; it < 16; ++it) {
        const int kf = h * 128 + it * 8 + og;   // float4 index within row
        const float4 xa = x4[xbase + kf];
        const float4 xb = x4[xbase + kf + 1];
        const float4 aa = A4[abase + kf];
        const float4 ab = A4[abase + kf + 1];

        const short8v af = pack8(xa, xb);       // 4 cvt_pk ops
        const short8v bf = pack8(aa, ab);       // 4 cvt_pk ops

        acc = __builtin_amdgcn_mfma_f32_16x16x32_bf16(af, bf, acc, 0, 0, 0);
    }

    // C layout: lane l reg v -> row (l>>4)*4+v, col l&15
    #pragma unroll
    for (int v = 0; v < 4; ++v) {
        const int orow = row0 + (lane >> 4) * 4 + v;
        tpart[((size_t)h * M_ROWS + orow) * 16 + (lane & 15)] = acc[v];
    }
}

// ---------------------------------------------------------------------------
// Kernel 2: out = t @ B^T using pre-transposed Bt (byte-identical to r13).
__global__ __launch_bounds__(256) void lora_tb(const float* __restrict__ tpart,
                                               const float* __restrict__ Bt,
                                               float* __restrict__ out) {
    __shared__ float4 tp_s[4][64];
    __shared__ float4 t_s4[64];           // 16 rows x 16 r

    const int tid = threadIdx.x;
    const int rb  = blockIdx.x >> 2;      // 16-row tile
    const int cb  = blockIdx.x & 3;       // 1024-col chunk
    const int c4  = cb * 256 + tid;       // float4 column index

    const float4* Bt4 = (const float4*)Bt;
    float4 bv[16];
    #pragma unroll
    for (int r = 0; r < 16; ++r)
        bv[r] = Bt4[r * NF + c4];         // 1KB contiguous per instr, L2-hot

    // parallel tpart sum: 8 slabs -> 4 partials -> 1
    {
        const int f  = tid & 63;
        const int hp = tid >> 6;          // 0..3
        const float4* p4 = (const float4*)tpart;
        float4 a = p4[(size_t)(2 * hp) * TP_F4_STRIDE + rb * 64 + f];
        const float4 b = p4[(size_t)(2 * hp + 1) * TP_F4_STRIDE + rb * 64 + f];
        a.x += b.x; a.y += b.y; a.z += b.z; a.w += b.w;
        tp_s[hp][f] = a;
    }
    __syncthreads();
    if (tid < 64) {
        float4 s = tp_s[0][tid];
        #pragma unroll
        for (int hp = 1; hp < 4; ++hp) {
            const float4 q = tp_s[hp][tid];
            s.x += q.x; s.y += q.y; s.z += q.z; s.w += q.w;
        }
        t_s4[tid] = s;                    // t[rb*16 + ...] row*4+q layout
    }
    __syncthreads();

    float4* out4 = (float4*)out;

    #pragma unroll
    for (int row = 0; row < 16; ++row) {
        float4 tq[4];
        #pragma unroll
        for (int q = 0; q < 4; ++q)
            tq[q] = t_s4[row * 4 + q];    // LDS broadcast (same addr all lanes)
        float4 o = {0.f, 0.f, 0.f, 0.f};
        #pragma unroll
        for (int r = 0; r < 16; ++r) {
            const float4 tv4 = tq[r >> 2];
            const float tv = ((r & 3) == 0) ? tv4.x :
                             ((r & 3) == 1) ? tv4.y :
                             ((r & 3) == 2) ? tv4.z : tv4.w;
            o.x = fmaf(tv, bv[r].x, o.x);
            o.y = fmaf(tv, bv[r].y, o.y);
            o.z = fmaf(tv, bv[r].z, o.z);
            o.w = fmaf(tv, bv[r].w, o.w);
        }
        out4[(size_t)(rb * 16 + row) * NF + c4] = o;
    }
}

extern "C" void kernel_launch(void* const* d_in, const int* in_sizes, int n_in,
                              void* d_out, int out_size, void* d_ws, size_t ws_size,
                              hipStream_t stream) {
    const float* x = (const float*)d_in[0];            // [4,2048,4096]
    const float* B = (const float*)d_in[1];            // [4096,16]
    const float* A = (const float*)d_in[2];            // [16,4096]
    float* out = (float*)d_out;                        // [4,2048,4096]

    float* Bt    = (float*)d_ws;                       // [16][4096], 256 KB
    float* tpart = Bt + 16 * N_DIM;                    // [8][8192][16], 4 MB

    lora_xat<<<XAT_BLOCKS + TRB_BLOCKS, 256, 0, stream>>>(x, A, B, Bt, tpart);
    lora_tb<<<NTILES * (N_DIM / 1024), 256, 0, stream>>>(tpart, Bt, out);
}

// Round 21
// 62.197 us; speedup vs baseline: 1.0638x; 1.0115x over previous
//
#include <hip/hip_runtime.h>

#define K_DIM   4096
#define N_DIM   4096
#define M_ROWS  8192
#define KF      (K_DIM / 4)      // 1024 float4 per x/A row
#define NF      (N_DIM / 4)      // 1024 float4 per out/Bt row
#define KSPLIT  8
#define NTILES  (M_ROWS / 16)    // 512 row tiles (k2 grid)
#define TP_F4_STRIDE (M_ROWS * 16 / 4)   // 32768 float4 per k-partial slab
#define XAT_BLOCKS ((M_ROWS / 32) * KSPLIT)   // 2048 compute blocks
#define TRB_BLOCKS 128                        // folded B-transpose blocks

typedef __attribute__((ext_vector_type(8))) short short8v;   // 8 bf16
typedef __attribute__((ext_vector_type(4))) float f32x4;
typedef __attribute__((ext_vector_type(4))) unsigned u32x4;

// v_cvt_pk_bf16_f32: packs 2 f32 -> 2 bf16 in one VGPR (lo = first src).
static __device__ __forceinline__ unsigned cvt_pk(float lo, float hi) {
    unsigned r;
    asm("v_cvt_pk_bf16_f32 %0, %1, %2" : "=v"(r) : "v"(lo), "v"(hi));
    return r;
}

// two float4 -> 8 bf16 (4 VGPRs) via 4 cvt_pk ops
static __device__ __forceinline__ short8v pack8(const float4 a, const float4 b) {
    u32x4 p;
    p[0] = cvt_pk(a.x, a.y);
    p[1] = cvt_pk(a.z, a.w);
    p[2] = cvt_pk(b.x, b.y);
    p[3] = cvt_pk(b.z, b.w);
    return __builtin_bit_cast(short8v, p);
}

// ---------------------------------------------------------------------------
// Kernel 1 (MFMA + folded B-transpose), round-21 occupancy fix:
//   2048 compute blocks of 128 thr (2 waves, 32-row tile, K-eighth each)
//   -> 8 blocks/CU; unroll 2 keeps in-flight float4 count at 8 (~32 regs),
//   targeting VGPR <= 64 so 8 waves/SIMD can co-reside (2x round-13 TLP).
// Blocks [2048, 2176): transpose B [4096][16] -> Bt [16][4096].
__global__ __launch_bounds__(128) void lora_xat(const float* __restrict__ x,
                                                const float* __restrict__ A,
                                                const float* __restrict__ B,
                                                float* __restrict__ Bt,
                                                float* __restrict__ tpart) {
    const int tid = threadIdx.x;          // 0..127

    if (blockIdx.x >= XAT_BLOCKS) {
        // ---- B transpose: 128 blocks x 128 thr x 1 float4 of Bt ----
        const int i4 = (blockIdx.x - XAT_BLOCKS) * 128 + tid;  // 0..16383
        const int r  = i4 >> 10;             // Bt row 0..15
        const int c0 = (i4 & 1023) * 4;      // first of 4 cols
        float4 v;
        v.x = B[(size_t)(c0 + 0) * 16 + r];
        v.y = B[(size_t)(c0 + 1) * 16 + r];
        v.z = B[(size_t)(c0 + 2) * 16 + r];
        v.w = B[(size_t)(c0 + 3) * 16 + r];
        ((float4*)Bt)[i4] = v;
        return;
    }

    const int wv   = tid >> 6;            // 0..1: 16-row half of the tile
    const int lane = tid & 63;
    const int rb   = blockIdx.x >> 3;     // 32-row tile 0..255
    const int h    = blockIdx.x & 7;      // K eighth
    const int row0 = rb * 32 + wv * 16;

    const int mrow = row0 + (lane & 15);  // x row this lane feeds (A-op)
    const int acol = lane & 15;           // A-matrix row = t column (B-op)
    const int og   = (lane >> 4) * 2;     // lane-group's float4 pair in octet

    const float4* x4 = (const float4*)x;
    const float4* A4 = (const float4*)A;
    const size_t xbase = (size_t)mrow * KF;
    const size_t abase = (size_t)acol * KF;

    f32x4 acc = {0.f, 0.f, 0.f, 0.f};

    #pragma unroll 2
    for (int it = 0; it < 16; ++it) {
        const int kf = h * 128 + it * 8 + og;   // float4 index within row
        const float4 xa = x4[xbase + kf];
        const float4 xb = x4[xbase + kf + 1];
        const float4 aa = A4[abase + kf];
        const float4 ab = A4[abase + kf + 1];

        const short8v af = pack8(xa, xb);       // 4 cvt_pk ops
        const short8v bf = pack8(aa, ab);       // 4 cvt_pk ops

        acc = __builtin_amdgcn_mfma_f32_16x16x32_bf16(af, bf, acc, 0, 0, 0);
    }

    // C layout: lane l reg v -> row (l>>4)*4+v, col l&15
    #pragma unroll
    for (int v = 0; v < 4; ++v) {
        const int orow = row0 + (lane >> 4) * 4 + v;
        tpart[((size_t)h * M_ROWS + orow) * 16 + (lane & 15)] = acc[v];
    }
}

// ---------------------------------------------------------------------------
// Kernel 2: out = t @ B^T using pre-transposed Bt (byte-identical to r13).
__global__ __launch_bounds__(256) void lora_tb(const float* __restrict__ tpart,
                                               const float* __restrict__ Bt,
                                               float* __restrict__ out) {
    __shared__ float4 tp_s[4][64];
    __shared__ float4 t_s4[64];           // 16 rows x 16 r

    const int tid = threadIdx.x;
    const int rb  = blockIdx.x >> 2;      // 16-row tile
    const int cb  = blockIdx.x & 3;       // 1024-col chunk
    const int c4  = cb * 256 + tid;       // float4 column index

    const float4* Bt4 = (const float4*)Bt;
    float4 bv[16];
    #pragma unroll
    for (int r = 0; r < 16; ++r)
        bv[r] = Bt4[r * NF + c4];         // 1KB contiguous per instr, L2-hot

    // parallel tpart sum: 8 slabs -> 4 partials -> 1
    {
        const int f  = tid & 63;
        const int hp = tid >> 6;          // 0..3
        const float4* p4 = (const float4*)tpart;
        float4 a = p4[(size_t)(2 * hp) * TP_F4_STRIDE + rb * 64 + f];
        const float4 b = p4[(size_t)(2 * hp + 1) * TP_F4_STRIDE + rb * 64 + f];
        a.x += b.x; a.y += b.y; a.z += b.z; a.w += b.w;
        tp_s[hp][f] = a;
    }
    __syncthreads();
    if (tid < 64) {
        float4 s = tp_s[0][tid];
        #pragma unroll
        for (int hp = 1; hp < 4; ++hp) {
            const float4 q = tp_s[hp][tid];
            s.x += q.x; s.y += q.y; s.z += q.z; s.w += q.w;
        }
        t_s4[tid] = s;                    // t[rb*16 + ...] row*4+q layout
    }
    __syncthreads();

    float4* out4 = (float4*)out;

    #pragma unroll
    for (int row = 0; row < 16; ++row) {
        float4 tq[4];
        #pragma unroll
        for (int q = 0; q < 4; ++q)
            tq[q] = t_s4[row * 4 + q];    // LDS broadcast (same addr all lanes)
        float4 o = {0.f, 0.f, 0.f, 0.f};
        #pragma unroll
        for (int r = 0; r < 16; ++r) {
            const float4 tv4 = tq[r >> 2];
            const float tv = ((r & 3) == 0) ? tv4.x :
                             ((r & 3) == 1) ? tv4.y :
                             ((r & 3) == 2) ? tv4.z : tv4.w;
            o.x = fmaf(tv, bv[r].x, o.x);
            o.y = fmaf(tv, bv[r].y, o.y);
            o.z = fmaf(tv, bv[r].z, o.z);
            o.w = fmaf(tv, bv[r].w, o.w);
        }
        out4[(size_t)(rb * 16 + row) * NF + c4] = o;
    }
}

extern "C" void kernel_launch(void* const* d_in, const int* in_sizes, int n_in,
                              void* d_out, int out_size, void* d_ws, size_t ws_size,
                              hipStream_t stream) {
    const float* x = (const float*)d_in[0];            // [4,2048,4096]
    const float* B = (const float*)d_in[1];            // [4096,16]
    const float* A = (const float*)d_in[2];            // [16,4096]
    float* out = (float*)d_out;                        // [4,2048,4096]

    float* Bt    = (float*)d_ws;                       // [16][4096], 256 KB
    float* tpart = Bt + 16 * N_DIM;                    // [8][8192][16], 4 MB

    lora_xat<<<XAT_BLOCKS + TRB_BLOCKS, 128, 0, stream>>>(x, A, B, Bt, tpart);
    lora_tb<<<NTILES * (N_DIM / 1024), 256, 0, stream>>>(tpart, Bt, out);
}